// Round 3
// baseline (2098.544 us; speedup 1.0000x reference)
//
#include <hip/hip_runtime.h>
#include <cstdint>

// ---------- types / helpers ----------
typedef __attribute__((ext_vector_type(8))) short short8;   // 8 x bf16 (4 VGPRs)
typedef __attribute__((ext_vector_type(4))) float f32x4;
typedef unsigned short us16;

#define DEV __device__ __forceinline__

DEV us16 f2bf(float f){
  union { float f; unsigned u; } v; v.f = f;
  unsigned r = (v.u + 0x7FFFu + ((v.u >> 16) & 1u)) >> 16;   // RNE
  return (us16)r;
}
DEV unsigned char f2fp8(float f){      // OCP e4m3fn via HW cvt (RNE, saturating)
  int p = __builtin_amdgcn_cvt_pk_fp8_f32(f, f, 0, false);
  return (unsigned char)(p & 0xFF);
}
DEV float fsig(float x){              // 1/(1+e^-x)
  float e = __builtin_amdgcn_exp2f(-1.4426950408889634f * x);
  return __builtin_amdgcn_rcpf(1.0f + e);
}
DEV float ftanh(float x){             // 2/(1+e^-2x) - 1
  float e = __builtin_amdgcn_exp2f(-2.8853900817779268f * x);
  return fmaf(2.0f, __builtin_amdgcn_rcpf(1.0f + e), -1.0f);
}
DEV float fsoftplus(float x){         // max(x,0) + ln(1+e^-|x|)
  float ax = fabsf(x);
  float e = __builtin_amdgcn_exp2f(-1.4426950408889634f * ax);
  float l = 0.69314718055994531f * __builtin_amdgcn_logf(1.0f + e);
  return fmaxf(x, 0.0f) + l;
}
DEV f32x4 mfma16(short8 a, short8 b, f32x4 c){
  return __builtin_amdgcn_mfma_f32_16x16x32_bf16(a, b, c, 0, 0, 0);
}
DEV f32x4 mfma16f8(long a, long b, f32x4 c){
  return __builtin_amdgcn_mfma_f32_16x16x32_fp8_fp8(a, b, c, 0, 0, 0);
}

// Dims: B=256, T=WN=200, HH=256 (per direction), gates=1024, K(tags)=12
// MFMA 16x16x32 fragment layouts (dtype-independent index mapping, HW-verified):
//   A: lane L holds A[m=L&15][k=(L>>4)*8+j], j=0..7
//   B: lane L holds B[k=(L>>4)*8+j][n=L&15]
//   D: lane L reg r holds D[row=(L>>4)*4+r][col=L&15]

// ---------- preprocessing kernels ----------

// char_vec[b][t][0..31] = fp8(char_emb[characters[b][t]][c]), pad c=30,31 -> 0
__global__ void k_embed(const int* __restrict__ chars, const float* __restrict__ emb,
                        unsigned char* __restrict__ out){
  int tid = blockIdx.x * 256 + threadIdx.x;          // 256*200*32
  if (tid >= 256*200*32) return;
  int c = tid & 31, bt = tid >> 5;
  int idx = chars[bt];
  float v = (c < 30) ? emb[idx * 30 + c] : 0.0f;
  out[tid] = f2fp8(v);
}

__global__ void k_cvt8(const float* __restrict__ src, unsigned char* __restrict__ dst, int n){
  int tid = blockIdx.x * 256 + threadIdx.x;
  if (tid < n) dst[tid] = f2fp8(src[tid]);
}

// LSTM combined weight [Whh | Wih] -> fp8, layout [w(16)][gt(4)][kc(KC)][lane(64) x 8B]
// gate row = gt*256 + w*16 + (L&15); k = kc*32 + (L>>4)*8 + j
__global__ void k_swz_lstm(const float* __restrict__ Whh, const float* __restrict__ Wih,
                           int I, int KC, unsigned char* __restrict__ dst){
  int tid = blockIdx.x * 256 + threadIdx.x;
  int total = 64 * KC * 512;
  if (tid >= total) return;
  int e = tid & 511, chunk = tid >> 9;
  int L = e >> 3, j = e & 7;
  int kc = chunk % KC; int rem = chunk / KC;
  int gt = rem & 3, w = rem >> 2;
  int g = gt * 256 + w * 16 + (L & 15);
  int k = kc * 32 + (L >> 4) * 8 + j;
  float v = 0.0f;
  if (k < 256) v = Whh[g * 256 + k];
  else if (k - 256 < I) v = Wih[g * I + (k - 256)];
  dst[tid] = f2fp8(v);
}

// FF weight swizzle (bf16): [ntile(NT)][kc(KC)][lane x 8], zero-padded past N/K
__global__ void k_swz_ff(const float* __restrict__ W, int N, int Kd, int KC,
                         us16* __restrict__ dst, int total){
  int tid = blockIdx.x * 256 + threadIdx.x;
  if (tid >= total) return;
  int e = tid & 511, chunk = tid >> 9;
  int L = e >> 3, j = e & 7;
  int kc = chunk % KC; int nt = chunk / KC;
  int g = nt * 16 + (L & 15);
  int k = kc * 32 + (L >> 4) * 8 + j;
  float v = (g < N && k < Kd) ? W[g * Kd + k] : 0.0f;
  dst[tid] = f2bf(v);
}

// zero the k-padding columns 712..735 of x_cat
__global__ void k_zpad(us16* __restrict__ xcat){
  int tid = blockIdx.x * 256 + threadIdx.x;          // 51200*24
  if (tid >= 51200 * 24) return;
  int r = tid / 24, c = tid - r * 24;
  xcat[r * 736 + 712 + c] = 0;
}

// ---------- bidirectional LSTM (fp8 recurrence) ----------
// grid = 32 blocks x 1024 threads (16 waves, 4/SIMD).
// dir = blockIdx>>3 (0 cf,1 cb,2 wf,3 wb), slice = blockIdx&7 (32 batch rows).
// Wave w owns h-column strip [w*16, w*16+16) and all 4 gate types for it.
// A-operand (h|x) is fp8 in LDS; weights fp8 streamed from L2; c state fp32 VGPR.
template<int KC, int XDIM, int SA>
DEV void lstm_body(unsigned char* abuf, const unsigned char* __restrict__ xbuf,
                   const unsigned char* __restrict__ Wsw, const float* __restrict__ bias,
                   const int* __restrict__ lens, us16* __restrict__ hout,
                   int b0, int hcol0, bool rev)
{
  const int tid = threadIdx.x;
  const int w = tid >> 6, L = tid & 63;
  const int lrow = L & 15, lq = L >> 4;

  for (int e = tid; e < 32 * 32; e += 1024)          // zero h region (32 rows x 256 B)
    *(long*)&abuf[(e >> 5) * SA + (e & 31) * 8] = 0;

  float bv[4];
  #pragma unroll
  for (int gt = 0; gt < 4; ++gt) bv[gt] = bias[gt * 256 + w * 16 + lrow];

  int lenv[2][4];
  #pragma unroll
  for (int m0 = 0; m0 < 2; ++m0)
    #pragma unroll
    for (int r = 0; r < 4; ++r)
      lenv[m0][r] = lens[b0 + m0 * 16 + lq * 4 + r];

  float cst[2][4];
  #pragma unroll
  for (int m0 = 0; m0 < 2; ++m0)
    #pragma unroll
    for (int r = 0; r < 4; ++r) cst[m0][r] = 0.0f;

  const int nch = (32 * XDIM) >> 3;                  // 8-byte chunks per timestep
  auto load_x = [&](int t){
    for (int ch = tid; ch < nch; ch += 1024){
      int r = ch / (XDIM >> 3);
      int c8 = (ch % (XDIM >> 3)) << 3;
      *(long*)&abuf[r * SA + 256 + c8] =
        *(const long*)&xbuf[((long)(b0 + r) * 200 + t) * XDIM + c8];
    }
  };
  load_x(rev ? 199 : 0);
  __syncthreads();

  const long* WswV = (const long*)Wsw;

  for (int tau = 0; tau < 200; ++tau){
    const int t = rev ? (199 - tau) : tau;
    f32x4 acc[4][2] = {};                // [gate type][m-tile]
    #pragma unroll 6
    for (int kc = 0; kc < KC; ++kc){
      long af0 = *(const long*)&abuf[lrow * SA + kc * 32 + lq * 8];
      long af1 = *(const long*)&abuf[(16 + lrow) * SA + kc * 32 + lq * 8];
      #pragma unroll
      for (int gt = 0; gt < 4; ++gt){
        long bf = WswV[((w * 4 + gt) * KC + kc) * 64 + L];
        acc[gt][0] = mfma16f8(af0, bf, acc[gt][0]);
        acc[gt][1] = mfma16f8(af1, bf, acc[gt][1]);
      }
    }
    __syncthreads();                     // all LDS reads of h/x for step t done
    const int col = w * 16 + lrow;
    #pragma unroll
    for (int m0 = 0; m0 < 2; ++m0){
      #pragma unroll
      for (int r = 0; r < 4; ++r){
        const int bm = m0 * 16 + lq * 4 + r;
        const bool mk = t < lenv[m0][r];
        const long gbase = ((long)(b0 + bm) * 200 + t) * 512 + hcol0;
        float gi = acc[0][m0][r] + bv[0];
        float gf = acc[1][m0][r] + bv[1];
        float gg = acc[2][m0][r] + bv[2];
        float go = acc[3][m0][r] + bv[3];
        float cn = fsig(gf) * cst[m0][r] + fsig(gi) * ftanh(gg);
        float hn = fsig(go) * ftanh(cn);
        if (mk){
          cst[m0][r] = cn;
          abuf[bm * SA + col] = f2fp8(hn);   // state for next step (fp8)
          hout[gbase + col] = f2bf(hn);      // masked output = hn (bf16 for FF)
        } else {
          hout[gbase + col] = 0;             // masked output = 0; state kept
        }
      }
    }
    if (tau < 199) load_x(rev ? (198 - tau) : (tau + 1));
    __syncthreads();
  }
}

__global__ __launch_bounds__(1024, 1) void k_lstm(
    const unsigned char* __restrict__ char_vec, const unsigned char* __restrict__ words_f8,
    const unsigned char* __restrict__ wsw_cf, const unsigned char* __restrict__ wsw_cb,
    const unsigned char* __restrict__ wsw_wf, const unsigned char* __restrict__ wsw_wb,
    const float* __restrict__ b_cf, const float* __restrict__ b_cb,
    const float* __restrict__ b_wf, const float* __restrict__ b_wb,
    const int* __restrict__ len_char, const int* __restrict__ len_word,
    us16* __restrict__ h_char, us16* __restrict__ h_word)
{
  const int dir   = blockIdx.x >> 3;
  const int slice = blockIdx.x & 7;
  const bool rev  = dir & 1;
  const int b0 = slice * 32;
  __shared__ __align__(16) unsigned char abuf[32 * 392];  // [32 rows][SA]: 0..255 h, 256.. x

  if (dir < 2){
    lstm_body<9, 32, 296>(abuf, char_vec, dir ? wsw_cb : wsw_cf,
                          dir ? b_cb : b_cf, len_char, h_char,
                          b0, rev ? 256 : 0, rev);
  } else {
    lstm_body<12, 128, 392>(abuf, words_f8, (dir == 3) ? wsw_wb : wsw_wf,
                            (dir == 3) ? b_wb : b_wf, len_word, h_word,
                            b0, rev ? 256 : 0, rev);
  }
}

// ---------- generic FF GEMM: out = softplus(A[M,K]bf16 @ Wsw^T + bias) ----------
__global__ __launch_bounds__(256) void k_gemm(
    const us16* __restrict__ A, int KC, const us16* __restrict__ Wsw,
    const float* __restrict__ bias, int N,
    void* __restrict__ outp, int ostride, int ocol0, int out_f32)
{
  const int tid = threadIdx.x;
  const int w = tid >> 6, L = tid & 63;
  const int lrow = L & 15, lq = L >> 4;
  const int m0base = blockIdx.x * 128;
  const int ntbase = blockIdx.y * 8;
  const int Kd = KC * 32;
  __shared__ us16 At[128 * 40];            // 20 dw stride -> <=2-way banks
  f32x4 acc[8][2] = {};
  const short8* WswV = (const short8*)Wsw;
  const int srow = tid >> 1, scol = (tid & 1) * 16;

  for (int kc = 0; kc < KC; ++kc){
    const long abase = (long)(m0base + srow) * Kd + kc * 32 + scol;
    short8 v0 = *(const short8*)&A[abase];
    short8 v1 = *(const short8*)&A[abase + 8];
    *(short8*)&At[srow * 40 + scol] = v0;
    *(short8*)&At[srow * 40 + scol + 8] = v1;
    __syncthreads();
    short8 af0 = *(const short8*)&At[(w * 32 + lrow) * 40 + lq * 8];
    short8 af1 = *(const short8*)&At[(w * 32 + 16 + lrow) * 40 + lq * 8];
    #pragma unroll
    for (int nt = 0; nt < 8; ++nt){
      short8 bf = WswV[((ntbase + nt) * KC + kc) * 64 + L];
      acc[nt][0] = mfma16(af0, bf, acc[nt][0]);
      acc[nt][1] = mfma16(af1, bf, acc[nt][1]);
    }
    __syncthreads();
  }
  #pragma unroll
  for (int nt = 0; nt < 8; ++nt){
    const int col = (ntbase + nt) * 16 + lrow;
    if (col >= N) continue;
    const float bvv = bias[col];
    #pragma unroll
    for (int m0 = 0; m0 < 2; ++m0){
      #pragma unroll
      for (int r = 0; r < 4; ++r){
        float v = fsoftplus(acc[nt][m0][r] + bvv);
        const int row = m0base + w * 32 + m0 * 16 + lq * 4 + r;
        if (out_f32) ((float*)outp)[(long)row * ostride + ocol0 + col] = v;
        else         ((us16*)outp)[(long)row * ostride + ocol0 + col] = f2bf(v);
      }
    }
  }
}

// ---------- CRF NLL: one wave per batch row ----------
__global__ void k_crf(const float* __restrict__ logits, const int* __restrict__ tags,
                      const int* __restrict__ lens, const float* __restrict__ trans,
                      float* __restrict__ nll)
{
  const int b = blockIdx.x;
  const int lane = threadIdx.x;            // 64
  __shared__ float alpha[12];
  __shared__ float tmp[12];
  float tcol[12];
  if (lane < 12){
    #pragma unroll
    for (int i = 0; i < 12; ++i) tcol[i] = trans[i * 12 + lane];
    alpha[lane] = 0.0f;
  }
  const int len = lens[b];
  __syncthreads();
  for (int t = 0; t < len; ++t){
    float an = 0.0f;
    if (lane < 12){
      float mx = -3.0e38f;
      #pragma unroll
      for (int i = 0; i < 12; ++i) mx = fmaxf(mx, alpha[i] + tcol[i]);
      float ss = 0.0f;
      #pragma unroll
      for (int i = 0; i < 12; ++i)
        ss += __builtin_amdgcn_exp2f(1.4426950408889634f * (alpha[i] + tcol[i] - mx));
      an = logits[((long)b * 200 + t) * 12 + lane] + mx
         + 0.69314718055994531f * __builtin_amdgcn_logf(ss);
    }
    __syncthreads();
    if (lane < 12) alpha[lane] = an;
    __syncthreads();
  }
  if (lane < 12) tmp[lane] = alpha[lane] + trans[lane * 12 + 11];   // + trans[:,STOP]
  __syncthreads();
  float rs = 0.0f;
  for (int t = lane; t < len; t += 64){
    int tg = tags[b * 200 + t];
    int pv = (t == 0) ? 10 : tags[b * 200 + t - 1];                 // START=10
    rs += logits[((long)b * 200 + t) * 12 + tg] + trans[pv * 12 + tg];
  }
  #pragma unroll
  for (int off = 32; off > 0; off >>= 1) rs += __shfl_down(rs, off, 64);
  if (lane == 0){
    float mx = -3.0e38f;
    for (int i = 0; i < 12; ++i) mx = fmaxf(mx, tmp[i]);
    float ss = 0.0f;
    for (int i = 0; i < 12; ++i)
      ss += __builtin_amdgcn_exp2f(1.4426950408889634f * (tmp[i] - mx));
    float total = mx + 0.69314718055994531f * __builtin_amdgcn_logf(ss);
    rs += trans[tags[b * 200 + len - 1] * 12 + 11];                 // trans[last, STOP]
    nll[b] = total - rs;
  }
}

__global__ void k_sum(const float* __restrict__ nll, float* __restrict__ out){
  __shared__ float red[256];
  int t = threadIdx.x;
  red[t] = nll[t];
  __syncthreads();
  for (int s = 128; s > 0; s >>= 1){
    if (t < s) red[t] += red[t + s];
    __syncthreads();
  }
  if (t == 0) out[0] = red[0];
}

// ---------- launcher ----------
extern "C" void kernel_launch(void* const* d_in, const int* in_sizes, int n_in,
                              void* d_out, int out_size, void* d_ws, size_t ws_size,
                              hipStream_t stream)
{
  (void)in_sizes; (void)n_in; (void)out_size; (void)ws_size;
  const int*   characters = (const int*)  d_in[0];
  const float* words      = (const float*)d_in[1];
  const int*   tags       = (const int*)  d_in[2];
  const int*   len_char   = (const int*)  d_in[3];
  const int*   len_word   = (const int*)  d_in[4];
  const float* char_emb   = (const float*)d_in[5];
  const float* char_Wih_f = (const float*)d_in[6];
  const float* char_Whh_f = (const float*)d_in[7];
  const float* char_b_f   = (const float*)d_in[8];
  const float* char_Wih_b = (const float*)d_in[9];
  const float* char_Whh_b = (const float*)d_in[10];
  const float* char_b_b   = (const float*)d_in[11];
  const float* char_lin_W = (const float*)d_in[12];
  const float* char_lin_b = (const float*)d_in[13];
  const float* word_Wih_f = (const float*)d_in[14];
  const float* word_Whh_f = (const float*)d_in[15];
  const float* word_b_f   = (const float*)d_in[16];
  const float* word_Wih_b = (const float*)d_in[17];
  const float* word_Whh_b = (const float*)d_in[18];
  const float* word_b_b   = (const float*)d_in[19];
  const float* word_lin_W = (const float*)d_in[20];
  const float* word_lin_b = (const float*)d_in[21];
  const float* lin1_W     = (const float*)d_in[22];
  const float* lin1_b     = (const float*)d_in[23];
  const float* lin2_W     = (const float*)d_in[24];
  const float* lin2_b     = (const float*)d_in[25];
  const float* tag_W      = (const float*)d_in[26];
  const float* tag_b      = (const float*)d_in[27];
  const float* trans      = (const float*)d_in[28];

  char* ws = (char*)d_ws;
  size_t off = 0;
  auto take = [&](size_t bytes) -> char* {
    char* p = ws + off;
    off = (off + bytes + 511) & ~(size_t)511;
    return p;
  };
  unsigned char* char_vec = (unsigned char*)take((size_t)256*200*32);   // 1.6 MB fp8
  unsigned char* words_f8 = (unsigned char*)take((size_t)256*200*128);  // 6.3 MB fp8
  us16* h_char   = (us16*)take((size_t)51200*512*2);       // 50 MB
  us16* h_word   = (us16*)take((size_t)51200*512*2);       // 50 MB
  us16* x_cat    = (us16*)take((size_t)51200*736*2);       // 71.9 MB
  unsigned char* wsw_cf = (unsigned char*)take((size_t)64*9*512);
  unsigned char* wsw_cb = (unsigned char*)take((size_t)64*9*512);
  unsigned char* wsw_wf = (unsigned char*)take((size_t)64*12*512);
  unsigned char* wsw_wb = (unsigned char*)take((size_t)64*12*512);
  us16* wswg1    = (us16*)take((size_t)32*16*512*2);
  us16* wswg2    = (us16*)take((size_t)16*16*512*2);
  us16* wswg3    = (us16*)take((size_t)32*23*512*2);
  us16* wswg4    = (us16*)take((size_t)16*16*512*2);
  us16* wswg5    = (us16*)take((size_t)8*8*512*2);
  float* logits  = (float*)take((size_t)51200*12*4);
  float* nll     = (float*)take((size_t)256*4);
  us16* x1 = h_char;   // dead after G1
  us16* x2 = h_word;   // dead after G2

  // preprocessing
  k_embed<<<6400, 256, 0, stream>>>(characters, char_emb, char_vec);
  k_cvt8<<<(256*200*128 + 255)/256, 256, 0, stream>>>(words, words_f8, 256*200*128);
  k_swz_lstm<<<(64*9*512 + 255)/256, 256, 0, stream>>>(char_Whh_f, char_Wih_f, 30, 9, wsw_cf);
  k_swz_lstm<<<(64*9*512 + 255)/256, 256, 0, stream>>>(char_Whh_b, char_Wih_b, 30, 9, wsw_cb);
  k_swz_lstm<<<(64*12*512 + 255)/256, 256, 0, stream>>>(word_Whh_f, word_Wih_f, 128, 12, wsw_wf);
  k_swz_lstm<<<(64*12*512 + 255)/256, 256, 0, stream>>>(word_Whh_b, word_Wih_b, 128, 12, wsw_wb);
  k_swz_ff<<<(32*16*512 + 255)/256, 256, 0, stream>>>(char_lin_W, 512, 512, 16, wswg1, 32*16*512);
  k_swz_ff<<<(16*16*512 + 255)/256, 256, 0, stream>>>(word_lin_W, 200, 512, 16, wswg2, 16*16*512);
  k_swz_ff<<<(32*23*512 + 255)/256, 256, 0, stream>>>(lin1_W, 512, 712, 23, wswg3, 32*23*512);
  k_swz_ff<<<(16*16*512 + 255)/256, 256, 0, stream>>>(lin2_W, 256, 512, 16, wswg4, 16*16*512);
  k_swz_ff<<<(8*8*512 + 255)/256, 256, 0, stream>>>(tag_W, 12, 256, 8, wswg5, 8*8*512);
  k_zpad<<<4800, 256, 0, stream>>>(x_cat);

  // recurrences (4 directions concurrent in one launch; 16 waves/block; fp8)
  k_lstm<<<32, 1024, 0, stream>>>(char_vec, words_f8, wsw_cf, wsw_cb, wsw_wf, wsw_wb,
                                  char_b_f, char_b_b, word_b_f, word_b_b,
                                  len_char, len_word, h_char, h_word);

  // feed-forward chain (bf16)
  k_gemm<<<dim3(400, 4), 256, 0, stream>>>(h_char, 16, wswg1, char_lin_b, 512, x_cat, 736,   0, 0);
  k_gemm<<<dim3(400, 2), 256, 0, stream>>>(h_word, 16, wswg2, word_lin_b, 200, x_cat, 736, 512, 0);
  k_gemm<<<dim3(400, 4), 256, 0, stream>>>(x_cat, 23, wswg3, lin1_b, 512, x1, 512, 0, 0);
  k_gemm<<<dim3(400, 2), 256, 0, stream>>>(x1,    16, wswg4, lin2_b, 256, x2, 256, 0, 0);
  k_gemm<<<dim3(400, 1), 256, 0, stream>>>(x2,     8, wswg5, tag_b,   12, logits, 12, 0, 1);

  // CRF
  k_crf<<<256, 64, 0, stream>>>(logits, tags, len_char, trans, nll);
  k_sum<<<1, 256, 0, stream>>>(nll, (float*)d_out);
}

// Round 4
// 1222.467 us; speedup vs baseline: 1.7166x; 1.7166x over previous
//
#include <hip/hip_runtime.h>
#include <cstdint>

// ---------- types / helpers ----------
typedef __attribute__((ext_vector_type(8))) short short8;   // 8 x bf16 (4 VGPRs)
typedef __attribute__((ext_vector_type(4))) float f32x4;
typedef unsigned short us16;
typedef unsigned char u8;

#define DEV __device__ __forceinline__

DEV us16 f2bf(float f){
  union { float f; unsigned u; } v; v.f = f;
  unsigned r = (v.u + 0x7FFFu + ((v.u >> 16) & 1u)) >> 16;   // RNE
  return (us16)r;
}
DEV u8 f2fp8(float f){      // OCP e4m3fn via HW cvt (RNE, saturating)
  int p = __builtin_amdgcn_cvt_pk_fp8_f32(f, f, 0, false);
  return (u8)(p & 0xFF);
}
DEV float fsig(float x){
  float e = __builtin_amdgcn_exp2f(-1.4426950408889634f * x);
  return __builtin_amdgcn_rcpf(1.0f + e);
}
DEV float ftanh(float x){
  float e = __builtin_amdgcn_exp2f(-2.8853900817779268f * x);
  return fmaf(2.0f, __builtin_amdgcn_rcpf(1.0f + e), -1.0f);
}
DEV float fsoftplus(float x){
  float ax = fabsf(x);
  float e = __builtin_amdgcn_exp2f(-1.4426950408889634f * ax);
  float l = 0.69314718055994531f * __builtin_amdgcn_logf(1.0f + e);
  return fmaxf(x, 0.0f) + l;
}
DEV f32x4 mfma16(short8 a, short8 b, f32x4 c){
  return __builtin_amdgcn_mfma_f32_16x16x32_bf16(a, b, c, 0, 0, 0);
}
DEV f32x4 mfma16f8(long a, long b, f32x4 c){
  return __builtin_amdgcn_mfma_f32_16x16x32_fp8_fp8(a, b, c, 0, 0, 0);
}

// Dims: B=256, T=WN=200, HH=256 (per direction), gates=1024, K(tags)=12
// MFMA 16x16x32 fragment layouts (dtype-independent, HW-verified):
//   A: lane L holds A[m=L&15][k=(L>>4)*8+j], j=0..7
//   B: lane L holds B[k=(L>>4)*8+j][n=L&15]
//   D: lane L reg r holds D[row=(L>>4)*4+r][col=L&15]

// ---------- preprocessing kernels ----------

__global__ void k_embed(const int* __restrict__ chars, const float* __restrict__ emb,
                        u8* __restrict__ out){
  int tid = blockIdx.x * 256 + threadIdx.x;          // 256*200*32
  if (tid >= 256*200*32) return;
  int c = tid & 31, bt = tid >> 5;
  int idx = chars[bt];
  float v = (c < 30) ? emb[idx * 30 + c] : 0.0f;
  out[tid] = f2fp8(v);
}

__global__ void k_cvt8(const float* __restrict__ src, u8* __restrict__ dst, int n){
  int tid = blockIdx.x * 256 + threadIdx.x;
  if (tid < n) dst[tid] = f2fp8(src[tid]);
}

// LSTM combined weight [Whh | Wih] -> fp8
// layout [w(8)][gt(4)][nt(2)][kc(KC)][lane(64) x 8B]
// gate row g = gt*256 + w*32 + nt*16 + (L&15); k = kc*32 + (L>>4)*8 + j
__global__ void k_swz_lstm(const float* __restrict__ Whh, const float* __restrict__ Wih,
                           int I, int KC, u8* __restrict__ dst){
  int tid = blockIdx.x * 256 + threadIdx.x;
  int total = 64 * KC * 512;
  if (tid >= total) return;
  int e = tid & 511, chunk = tid >> 9;
  int L = e >> 3, j = e & 7;
  int kc = chunk % KC; int rem = chunk / KC;
  int nt = rem & 1, gt = (rem >> 1) & 3, w = rem >> 3;
  int g = gt * 256 + w * 32 + nt * 16 + (L & 15);
  int k = kc * 32 + (L >> 4) * 8 + j;
  float v = 0.0f;
  if (k < 256) v = Whh[g * 256 + k];
  else if (k - 256 < I) v = Wih[g * I + (k - 256)];
  dst[tid] = f2fp8(v);
}

// FF weight swizzle (bf16): [ntile(NT)][kc(KC)][lane x 8], zero-padded past N/K
__global__ void k_swz_ff(const float* __restrict__ W, int N, int Kd, int KC,
                         us16* __restrict__ dst, int total){
  int tid = blockIdx.x * 256 + threadIdx.x;
  if (tid >= total) return;
  int e = tid & 511, chunk = tid >> 9;
  int L = e >> 3, j = e & 7;
  int kc = chunk % KC; int nt = chunk / KC;
  int g = nt * 16 + (L & 15);
  int k = kc * 32 + (L >> 4) * 8 + j;
  float v = (g < N && k < Kd) ? W[g * Kd + k] : 0.0f;
  dst[tid] = f2bf(v);
}

// zero the k-padding columns 712..735 of x_cat
__global__ void k_zpad(us16* __restrict__ xcat){
  int tid = blockIdx.x * 256 + threadIdx.x;          // 51200*24
  if (tid >= 51200 * 24) return;
  int r = tid / 24, c = tid - r * 24;
  xcat[r * 736 + 712 + c] = 0;
}

// ---------- bidirectional LSTM (register-resident fp8 weights) ----------
// grid = 64 blocks x 512 threads (8 waves, 2/SIMD). dir = blockIdx>>4,
// slice = blockIdx&15 (16 batch rows). Wave w owns h-columns [w*32, w*32+32)
// (2 n-tiles) x 4 gate types. Resident weights: first KRES kc-chunks live in
// VGPRs for the whole 200-step loop (char: all 9; word: 8 = h-part). Word's
// x-part (4 kc) is re-streamed per step, issued at step-top and hidden behind
// the 64 resident-weight MFMAs. No per-step dependent L2 round-trips remain.
template<int KC, int KRES, int XDIM, int SA>
DEV void lstm_body(u8* abuf, float* sbias, const u8* __restrict__ xbuf,
                   const u8* __restrict__ Wsw, const float* __restrict__ bias,
                   const int* __restrict__ lens, us16* __restrict__ hout,
                   int b0, int hcol0, bool rev)
{
  constexpr int KSTR = KC - KRES;
  const int tid = threadIdx.x;
  const int w = tid >> 6, L = tid & 63;
  const int lrow = L & 15, lq = L >> 4;
  const long* WswV = (const long*)Wsw;

  // bias -> LDS
  for (int i = tid; i < 1024; i += 512) sbias[i] = bias[i];
  // zero h region (16 rows x 256 B)
  for (int e = tid; e < 16 * 32; e += 512)
    *(long*)&abuf[(e >> 5) * SA + (e & 31) * 8] = 0;

  // resident weights (static indices -> VGPRs)
  long wr[4][2][KRES];
  #pragma unroll
  for (int gt = 0; gt < 4; ++gt)
    #pragma unroll
    for (int nt = 0; nt < 2; ++nt)
      #pragma unroll
      for (int kc = 0; kc < KRES; ++kc)
        wr[gt][nt][kc] = WswV[(((w * 4 + gt) * 2 + nt) * KC + kc) * 64 + L];

  unsigned lpack = 0;                      // lens for D-rows lq*4+r, 8b each
  #pragma unroll
  for (int r = 0; r < 4; ++r)
    lpack |= (unsigned)lens[b0 + lq * 4 + r] << (8 * r);

  float cst[2][4];
  #pragma unroll
  for (int nt = 0; nt < 2; ++nt)
    #pragma unroll
    for (int r = 0; r < 4; ++r) cst[nt][r] = 0.0f;

  constexpr int NCH = (16 * XDIM) >> 3;    // 8B chunks per timestep
  auto load_x = [&](int t){
    if (tid < NCH){
      int r = tid / (XDIM >> 3);
      int c8 = (tid % (XDIM >> 3)) << 3;
      *(long*)&abuf[r * SA + 256 + c8] =
        *(const long*)&xbuf[((long)(b0 + r) * 200 + t) * XDIM + c8];
    }
  };
  load_x(rev ? 199 : 0);
  __syncthreads();

  for (int tau = 0; tau < 200; ++tau){
    const int t = rev ? (199 - tau) : tau;

    // streamed x-part weights for this step (word only) — issued first,
    // consumed after the resident MFMA block: latency hidden
    long xw[4][2][KSTR > 0 ? KSTR : 1];
    if constexpr (KSTR > 0){
      #pragma unroll
      for (int gt = 0; gt < 4; ++gt)
        #pragma unroll
        for (int nt = 0; nt < 2; ++nt)
          #pragma unroll
          for (int ks = 0; ks < KSTR; ++ks)
            xw[gt][nt][ks] = WswV[(((w * 4 + gt) * 2 + nt) * KC + KRES + ks) * 64 + L];
    }

    f32x4 acc[4][2];
    #pragma unroll
    for (int gt = 0; gt < 4; ++gt)
      #pragma unroll
      for (int nt = 0; nt < 2; ++nt){
        float b = sbias[gt * 256 + w * 32 + nt * 16 + lrow];
        acc[gt][nt] = (f32x4){b, b, b, b};
      }

    #pragma unroll
    for (int kc = 0; kc < KRES; ++kc){
      long af = *(const long*)&abuf[lrow * SA + kc * 32 + lq * 8];
      #pragma unroll
      for (int gt = 0; gt < 4; ++gt)
        #pragma unroll
        for (int nt = 0; nt < 2; ++nt)
          acc[gt][nt] = mfma16f8(af, wr[gt][nt][kc], acc[gt][nt]);
    }
    if constexpr (KSTR > 0){
      #pragma unroll
      for (int ks = 0; ks < KSTR; ++ks){
        long af = *(const long*)&abuf[lrow * SA + (KRES + ks) * 32 + lq * 8];
        #pragma unroll
        for (int gt = 0; gt < 4; ++gt)
          #pragma unroll
          for (int nt = 0; nt < 2; ++nt)
            acc[gt][nt] = mfma16f8(af, xw[gt][nt][ks], acc[gt][nt]);
      }
    }
    __syncthreads();                       // all LDS reads for step t done

    #pragma unroll
    for (int r = 0; r < 4; ++r){
      const int bm = lq * 4 + r;
      const bool mk = t < (int)((lpack >> (8 * r)) & 255u);
      const long gbase = ((long)(b0 + bm) * 200 + t) * 512 + hcol0;
      #pragma unroll
      for (int nt = 0; nt < 2; ++nt){
        float gi = acc[0][nt][r];
        float gf = acc[1][nt][r];
        float gg = acc[2][nt][r];
        float go = acc[3][nt][r];
        float cn = fsig(gf) * cst[nt][r] + fsig(gi) * ftanh(gg);
        float hn = fsig(go) * ftanh(cn);
        const int col = w * 32 + nt * 16 + lrow;
        if (mk){
          cst[nt][r] = cn;
          abuf[bm * SA + col] = f2fp8(hn);   // state for next step (fp8)
          hout[gbase + col] = f2bf(hn);      // masked output = hn
        } else {
          hout[gbase + col] = 0;             // masked output = 0; state kept
        }
      }
    }
    if (tau < 199) load_x(rev ? (198 - tau) : (tau + 1));
    __syncthreads();
  }
}

__global__ __launch_bounds__(512, 2) void k_lstm(
    const u8* __restrict__ char_vec, const u8* __restrict__ words_f8,
    const u8* __restrict__ wsw_cf, const u8* __restrict__ wsw_cb,
    const u8* __restrict__ wsw_wf, const u8* __restrict__ wsw_wb,
    const float* __restrict__ b_cf, const float* __restrict__ b_cb,
    const float* __restrict__ b_wf, const float* __restrict__ b_wb,
    const int* __restrict__ len_char, const int* __restrict__ len_word,
    us16* __restrict__ h_char, us16* __restrict__ h_word)
{
  const int dir   = blockIdx.x >> 4;
  const int slice = blockIdx.x & 15;
  const bool rev  = dir & 1;
  const int b0 = slice * 16;
  __shared__ __align__(16) u8 abuf[16 * 392];   // [16 rows][SA]: 0..255 h, 256.. x
  __shared__ float sbias[1024];

  if (dir < 2){
    lstm_body<9, 9, 32, 296>(abuf, sbias, char_vec, dir ? wsw_cb : wsw_cf,
                             dir ? b_cb : b_cf, len_char, h_char,
                             b0, rev ? 256 : 0, rev);
  } else {
    lstm_body<12, 8, 128, 392>(abuf, sbias, words_f8, (dir == 3) ? wsw_wb : wsw_wf,
                               (dir == 3) ? b_wb : b_wf, len_word, h_word,
                               b0, rev ? 256 : 0, rev);
  }
}

// ---------- generic FF GEMM: out = softplus(A[M,K]bf16 @ Wsw^T + bias) ----------
__global__ __launch_bounds__(256) void k_gemm(
    const us16* __restrict__ A, int KC, const us16* __restrict__ Wsw,
    const float* __restrict__ bias, int N,
    void* __restrict__ outp, int ostride, int ocol0, int out_f32)
{
  const int tid = threadIdx.x;
  const int w = tid >> 6, L = tid & 63;
  const int lrow = L & 15, lq = L >> 4;
  const int m0base = blockIdx.x * 128;
  const int ntbase = blockIdx.y * 8;
  const int Kd = KC * 32;
  __shared__ us16 At[128 * 40];            // 20 dw stride -> <=2-way banks
  f32x4 acc[8][2] = {};
  const short8* WswV = (const short8*)Wsw;
  const int srow = tid >> 1, scol = (tid & 1) * 16;

  for (int kc = 0; kc < KC; ++kc){
    const long abase = (long)(m0base + srow) * Kd + kc * 32 + scol;
    short8 v0 = *(const short8*)&A[abase];
    short8 v1 = *(const short8*)&A[abase + 8];
    *(short8*)&At[srow * 40 + scol] = v0;
    *(short8*)&At[srow * 40 + scol + 8] = v1;
    __syncthreads();
    short8 af0 = *(const short8*)&At[(w * 32 + lrow) * 40 + lq * 8];
    short8 af1 = *(const short8*)&At[(w * 32 + 16 + lrow) * 40 + lq * 8];
    #pragma unroll
    for (int nt = 0; nt < 8; ++nt){
      short8 bf = WswV[((ntbase + nt) * KC + kc) * 64 + L];
      acc[nt][0] = mfma16(af0, bf, acc[nt][0]);
      acc[nt][1] = mfma16(af1, bf, acc[nt][1]);
    }
    __syncthreads();
  }
  #pragma unroll
  for (int nt = 0; nt < 8; ++nt){
    const int col = (ntbase + nt) * 16 + lrow;
    if (col >= N) continue;
    const float bvv = bias[col];
    #pragma unroll
    for (int m0 = 0; m0 < 2; ++m0){
      #pragma unroll
      for (int r = 0; r < 4; ++r){
        float v = fsoftplus(acc[nt][m0][r] + bvv);
        const int row = m0base + w * 32 + m0 * 16 + lq * 4 + r;
        if (out_f32) ((float*)outp)[(long)row * ostride + ocol0 + col] = v;
        else         ((us16*)outp)[(long)row * ostride + ocol0 + col] = f2bf(v);
      }
    }
  }
}

// ---------- CRF NLL: one wave per batch row ----------
__global__ void k_crf(const float* __restrict__ logits, const int* __restrict__ tags,
                      const int* __restrict__ lens, const float* __restrict__ trans,
                      float* __restrict__ nll)
{
  const int b = blockIdx.x;
  const int lane = threadIdx.x;            // 64
  __shared__ float alpha[12];
  __shared__ float tmp[12];
  float tcol[12];
  if (lane < 12){
    #pragma unroll
    for (int i = 0; i < 12; ++i) tcol[i] = trans[i * 12 + lane];
    alpha[lane] = 0.0f;
  }
  const int len = lens[b];
  __syncthreads();
  for (int t = 0; t < len; ++t){
    float an = 0.0f;
    if (lane < 12){
      float mx = -3.0e38f;
      #pragma unroll
      for (int i = 0; i < 12; ++i) mx = fmaxf(mx, alpha[i] + tcol[i]);
      float ss = 0.0f;
      #pragma unroll
      for (int i = 0; i < 12; ++i)
        ss += __builtin_amdgcn_exp2f(1.4426950408889634f * (alpha[i] + tcol[i] - mx));
      an = logits[((long)b * 200 + t) * 12 + lane] + mx
         + 0.69314718055994531f * __builtin_amdgcn_logf(ss);
    }
    __syncthreads();
    if (lane < 12) alpha[lane] = an;
    __syncthreads();
  }
  if (lane < 12) tmp[lane] = alpha[lane] + trans[lane * 12 + 11];   // + trans[:,STOP]
  __syncthreads();
  float rs = 0.0f;
  for (int t = lane; t < len; t += 64){
    int tg = tags[b * 200 + t];
    int pv = (t == 0) ? 10 : tags[b * 200 + t - 1];                 // START=10
    rs += logits[((long)b * 200 + t) * 12 + tg] + trans[pv * 12 + tg];
  }
  #pragma unroll
  for (int off = 32; off > 0; off >>= 1) rs += __shfl_down(rs, off, 64);
  if (lane == 0){
    float mx = -3.0e38f;
    for (int i = 0; i < 12; ++i) mx = fmaxf(mx, tmp[i]);
    float ss = 0.0f;
    for (int i = 0; i < 12; ++i)
      ss += __builtin_amdgcn_exp2f(1.4426950408889634f * (tmp[i] - mx));
    float total = mx + 0.69314718055994531f * __builtin_amdgcn_logf(ss);
    rs += trans[tags[b * 200 + len - 1] * 12 + 11];                 // trans[last, STOP]
    nll[b] = total - rs;
  }
}

__global__ void k_sum(const float* __restrict__ nll, float* __restrict__ out){
  __shared__ float red[256];
  int t = threadIdx.x;
  red[t] = nll[t];
  __syncthreads();
  for (int s = 128; s > 0; s >>= 1){
    if (t < s) red[t] += red[t + s];
    __syncthreads();
  }
  if (t == 0) out[0] = red[0];
}

// ---------- launcher ----------
extern "C" void kernel_launch(void* const* d_in, const int* in_sizes, int n_in,
                              void* d_out, int out_size, void* d_ws, size_t ws_size,
                              hipStream_t stream)
{
  (void)in_sizes; (void)n_in; (void)out_size; (void)ws_size;
  const int*   characters = (const int*)  d_in[0];
  const float* words      = (const float*)d_in[1];
  const int*   tags       = (const int*)  d_in[2];
  const int*   len_char   = (const int*)  d_in[3];
  const int*   len_word   = (const int*)  d_in[4];
  const float* char_emb   = (const float*)d_in[5];
  const float* char_Wih_f = (const float*)d_in[6];
  const float* char_Whh_f = (const float*)d_in[7];
  const float* char_b_f   = (const float*)d_in[8];
  const float* char_Wih_b = (const float*)d_in[9];
  const float* char_Whh_b = (const float*)d_in[10];
  const float* char_b_b   = (const float*)d_in[11];
  const float* char_lin_W = (const float*)d_in[12];
  const float* char_lin_b = (const float*)d_in[13];
  const float* word_Wih_f = (const float*)d_in[14];
  const float* word_Whh_f = (const float*)d_in[15];
  const float* word_b_f   = (const float*)d_in[16];
  const float* word_Wih_b = (const float*)d_in[17];
  const float* word_Whh_b = (const float*)d_in[18];
  const float* word_b_b   = (const float*)d_in[19];
  const float* word_lin_W = (const float*)d_in[20];
  const float* word_lin_b = (const float*)d_in[21];
  const float* lin1_W     = (const float*)d_in[22];
  const float* lin1_b     = (const float*)d_in[23];
  const float* lin2_W     = (const float*)d_in[24];
  const float* lin2_b     = (const float*)d_in[25];
  const float* tag_W      = (const float*)d_in[26];
  const float* tag_b      = (const float*)d_in[27];
  const float* trans      = (const float*)d_in[28];

  char* ws = (char*)d_ws;
  size_t off = 0;
  auto take = [&](size_t bytes) -> char* {
    char* p = ws + off;
    off = (off + bytes + 511) & ~(size_t)511;
    return p;
  };
  u8*   char_vec = (u8*)take((size_t)256*200*32);          // 1.6 MB fp8
  u8*   words_f8 = (u8*)take((size_t)256*200*128);         // 6.3 MB fp8
  us16* h_char   = (us16*)take((size_t)51200*512*2);       // 50 MB
  us16* h_word   = (us16*)take((size_t)51200*512*2);       // 50 MB
  us16* x_cat    = (us16*)take((size_t)51200*736*2);       // 71.9 MB
  u8*   wsw_cf   = (u8*)take((size_t)64*9*512);
  u8*   wsw_cb   = (u8*)take((size_t)64*9*512);
  u8*   wsw_wf   = (u8*)take((size_t)64*12*512);
  u8*   wsw_wb   = (u8*)take((size_t)64*12*512);
  us16* wswg1    = (us16*)take((size_t)32*16*512*2);
  us16* wswg2    = (us16*)take((size_t)16*16*512*2);
  us16* wswg3    = (us16*)take((size_t)32*23*512*2);
  us16* wswg4    = (us16*)take((size_t)16*16*512*2);
  us16* wswg5    = (us16*)take((size_t)8*8*512*2);
  float* logits  = (float*)take((size_t)51200*12*4);
  float* nll     = (float*)take((size_t)256*4);
  us16* x1 = h_char;   // dead after G1
  us16* x2 = h_word;   // dead after G2

  // preprocessing
  k_embed<<<6400, 256, 0, stream>>>(characters, char_emb, char_vec);
  k_cvt8<<<(256*200*128 + 255)/256, 256, 0, stream>>>(words, words_f8, 256*200*128);
  k_swz_lstm<<<(64*9*512 + 255)/256, 256, 0, stream>>>(char_Whh_f, char_Wih_f, 30, 9, wsw_cf);
  k_swz_lstm<<<(64*9*512 + 255)/256, 256, 0, stream>>>(char_Whh_b, char_Wih_b, 30, 9, wsw_cb);
  k_swz_lstm<<<(64*12*512 + 255)/256, 256, 0, stream>>>(word_Whh_f, word_Wih_f, 128, 12, wsw_wf);
  k_swz_lstm<<<(64*12*512 + 255)/256, 256, 0, stream>>>(word_Whh_b, word_Wih_b, 128, 12, wsw_wb);
  k_swz_ff<<<(32*16*512 + 255)/256, 256, 0, stream>>>(char_lin_W, 512, 512, 16, wswg1, 32*16*512);
  k_swz_ff<<<(16*16*512 + 255)/256, 256, 0, stream>>>(word_lin_W, 200, 512, 16, wswg2, 16*16*512);
  k_swz_ff<<<(32*23*512 + 255)/256, 256, 0, stream>>>(lin1_W, 512, 712, 23, wswg3, 32*23*512);
  k_swz_ff<<<(16*16*512 + 255)/256, 256, 0, stream>>>(lin2_W, 256, 512, 16, wswg4, 16*16*512);
  k_swz_ff<<<(8*8*512 + 255)/256, 256, 0, stream>>>(tag_W, 12, 256, 8, wswg5, 8*8*512);
  k_zpad<<<4800, 256, 0, stream>>>(x_cat);

  // recurrences: 64 blocks x 512 thr, register-resident weights
  k_lstm<<<64, 512, 0, stream>>>(char_vec, words_f8, wsw_cf, wsw_cb, wsw_wf, wsw_wb,
                                 char_b_f, char_b_b, word_b_f, word_b_b,
                                 len_char, len_word, h_char, h_word);

  // feed-forward chain (bf16)
  k_gemm<<<dim3(400, 4), 256, 0, stream>>>(h_char, 16, wswg1, char_lin_b, 512, x_cat, 736,   0, 0);
  k_gemm<<<dim3(400, 2), 256, 0, stream>>>(h_word, 16, wswg2, word_lin_b, 200, x_cat, 736, 512, 0);
  k_gemm<<<dim3(400, 4), 256, 0, stream>>>(x_cat, 23, wswg3, lin1_b, 512, x1, 512, 0, 0);
  k_gemm<<<dim3(400, 2), 256, 0, stream>>>(x1,    16, wswg4, lin2_b, 256, x2, 256, 0, 0);
  k_gemm<<<dim3(400, 1), 256, 0, stream>>>(x2,     8, wswg5, tag_b,   12, logits, 12, 0, 1);

  // CRF
  k_crf<<<256, 64, 0, stream>>>(logits, tags, len_char, trans, nll);
  k_sum<<<1, 256, 0, stream>>>(nll, (float*)d_out);
}

// Round 5
// 1034.962 us; speedup vs baseline: 2.0277x; 1.1812x over previous
//
#include <hip/hip_runtime.h>
#include <cstdint>

// ---------- types / helpers ----------
typedef __attribute__((ext_vector_type(8))) short short8;   // 8 x bf16 (4 VGPRs)
typedef __attribute__((ext_vector_type(4))) float f32x4;
typedef __attribute__((ext_vector_type(4))) int i32x4;
typedef unsigned short us16;
typedef unsigned char u8;

#define DEV __device__ __forceinline__

DEV us16 f2bf(float f){
  union { float f; unsigned u; } v; v.f = f;
  unsigned r = (v.u + 0x7FFFu + ((v.u >> 16) & 1u)) >> 16;   // RNE
  return (us16)r;
}
DEV u8 f2fp8(float f){      // OCP e4m3fn via HW cvt (RNE, saturating)
  int p = __builtin_amdgcn_cvt_pk_fp8_f32(f, f, 0, false);
  return (u8)(p & 0xFF);
}
template<int SEL> DEV float fp8tof(int dw){
#if __has_builtin(__builtin_amdgcn_cvt_f32_fp8)
  return __builtin_amdgcn_cvt_f32_fp8(dw, SEL);
#else
  int b = (dw >> (8*SEL)) & 255;
  int e = (b>>3)&15, m = b&7;
  float v;
  if (e){ union{unsigned u; float f;} x; x.u = (unsigned)(((e+120)<<23) | (m<<20)); v = x.f; }
  else v = (float)m * 0.001953125f;
  return (b & 128) ? -v : v;
#endif
}
DEV float fsig(float x){
  float e = __builtin_amdgcn_exp2f(-1.4426950408889634f * x);
  return __builtin_amdgcn_rcpf(1.0f + e);
}
DEV float ftanh(float x){
  float e = __builtin_amdgcn_exp2f(-2.8853900817779268f * x);
  return fmaf(2.0f, __builtin_amdgcn_rcpf(1.0f + e), -1.0f);
}
DEV float fsoftplus(float x){
  float ax = fabsf(x);
  float e = __builtin_amdgcn_exp2f(-1.4426950408889634f * ax);
  float l = 0.69314718055994531f * __builtin_amdgcn_logf(1.0f + e);
  return fmaxf(x, 0.0f) + l;
}
DEV f32x4 mfma16(short8 a, short8 b, f32x4 c){
  return __builtin_amdgcn_mfma_f32_16x16x32_bf16(a, b, c, 0, 0, 0);
}
DEV f32x4 mfma16f8(long a, long b, f32x4 c){
  return __builtin_amdgcn_mfma_f32_16x16x32_fp8_fp8(a, b, c, 0, 0, 0);
}

// Dims: B=256, T=WN=200, HH=256 (per direction), gates=1024, K(tags)=12
// MFMA 16x16x32 fragment layouts (dtype-independent, HW-verified):
//   A: lane L holds A[m=L&15][k=(L>>4)*8+j], j=0..7
//   B: lane L holds B[k=(L>>4)*8+j][n=L&15]
//   D: lane L reg r holds D[row=(L>>4)*4+r][col=L&15]

// ---------- preprocessing kernels ----------

__global__ void k_embed(const int* __restrict__ chars, const float* __restrict__ emb,
                        u8* __restrict__ out){
  int tid = blockIdx.x * 256 + threadIdx.x;          // 256*200*32
  if (tid >= 256*200*32) return;
  int c = tid & 31, bt = tid >> 5;
  int idx = chars[bt];
  float v = (c < 30) ? emb[idx * 30 + c] : 0.0f;
  out[tid] = f2fp8(v);
}

__global__ void k_cvt8(const float* __restrict__ src, u8* __restrict__ dst, int n){
  int tid = blockIdx.x * 256 + threadIdx.x;
  if (tid < n) dst[tid] = f2fp8(src[tid]);
}

// LSTM combined weight [Whh | Wih] -> fp8
// layout [w(8)][gt(4)][nt(2)][kc(KC)][lane(64) x 8B]
// gate row g = gt*256 + w*32 + nt*16 + (L&15); k = kc*32 + (L>>4)*8 + j
__global__ void k_swz_lstm(const float* __restrict__ Whh, const float* __restrict__ Wih,
                           int I, int KC, u8* __restrict__ dst){
  int tid = blockIdx.x * 256 + threadIdx.x;
  int total = 64 * KC * 512;
  if (tid >= total) return;
  int e = tid & 511, chunk = tid >> 9;
  int L = e >> 3, j = e & 7;
  int kc = chunk % KC; int rem = chunk / KC;
  int nt = rem & 1, gt = (rem >> 1) & 3, w = rem >> 3;
  int g = gt * 256 + w * 32 + nt * 16 + (L & 15);
  int k = kc * 32 + (L >> 4) * 8 + j;
  float v = 0.0f;
  if (k < 256) v = Whh[g * 256 + k];
  else if (k - 256 < I) v = Wih[g * I + (k - 256)];
  dst[tid] = f2fp8(v);
}

// Wih (word, [1024 x 128]) B-fragment swizzle: [ntile(64)][kc(4)][lane x 8B]
__global__ void k_swz_gin(const float* __restrict__ Wih, u8* __restrict__ dst){
  int tid = blockIdx.x * 256 + threadIdx.x;          // 64*4*512
  if (tid >= 64*4*512) return;
  int e = tid & 511, chunk = tid >> 9;
  int L = e >> 3, j = e & 7;
  int kc = chunk & 3, ntile = chunk >> 2;
  int g = ntile * 16 + (L & 15);
  int k = kc * 32 + (L >> 4) * 8 + j;
  dst[tid] = f2fp8(Wih[g * 128 + k]);
}

// FF weight swizzle (bf16): [ntile(NT)][kc(KC)][lane x 8], zero-padded past N/K
__global__ void k_swz_ff(const float* __restrict__ W, int N, int Kd, int KC,
                         us16* __restrict__ dst, int total){
  int tid = blockIdx.x * 256 + threadIdx.x;
  if (tid >= total) return;
  int e = tid & 511, chunk = tid >> 9;
  int L = e >> 3, j = e & 7;
  int kc = chunk % KC; int nt = chunk / KC;
  int g = nt * 16 + (L & 15);
  int k = kc * 32 + (L >> 4) * 8 + j;
  float v = (g < N && k < Kd) ? W[g * Kd + k] : 0.0f;
  dst[tid] = f2bf(v);
}

// zero the k-padding columns 712..735 of x_cat  (runs AFTER k_lstm: x_cat aliases gin)
__global__ void k_zpad(us16* __restrict__ xcat){
  int tid = blockIdx.x * 256 + threadIdx.x;          // 51200*24
  if (tid >= 51200 * 24) return;
  int r = tid / 24, c = tid - r * 24;
  xcat[r * 736 + 712 + c] = 0;
}

// ---------- gin precompute: gin = fp8(x @ Wih^T + b) for both word directions ----------
// grid = 2*16*200 blocks x 512 thr. Block (d, slice, t): M=16 rows, N=1024, K=128.
// Output layout matches k_lstm consumption exactly: [(d*16+slice)*200+t][tid(512)][32B]
// where the 32 bytes of thread tid=(w,L) are cells [gt(4)][nt(2)][r(4)].
__global__ __launch_bounds__(512) void k_gin(
    const u8* __restrict__ words_f8, const u8* __restrict__ wswg_f,
    const u8* __restrict__ wswg_b, const float* __restrict__ bias_f,
    const float* __restrict__ bias_b, u8* __restrict__ gin)
{
  const int blk = blockIdx.x;
  const int d = blk >= 3200;
  const int rem = blk - d * 3200;
  const int slice = rem / 200, t = rem - slice * 200;
  const u8* Wsw = d ? wswg_b : wswg_f;
  const float* bias = d ? bias_b : bias_f;
  __shared__ u8 xs[16 * 136];
  __shared__ u8 sbuf[512 * 32];
  const int tid = threadIdx.x;
  const int wv = tid >> 6, L = tid & 63;
  const int lrow = L & 15, lq = L >> 4;
  if (tid < 256){
    int r = tid >> 4, c8 = (tid & 15) * 8;
    *(long*)&xs[r * 136 + c8] =
      *(const long*)&words_f8[((long)(slice * 16 + r) * 200 + t) * 128 + c8];
  }
  __syncthreads();
  const long* WswV = (const long*)Wsw;
  f32x4 acc[8];
  #pragma unroll
  for (int nt = 0; nt < 8; ++nt){
    float b = bias[wv * 128 + nt * 16 + lrow];
    acc[nt] = (f32x4){b, b, b, b};
  }
  #pragma unroll
  for (int kc = 0; kc < 4; ++kc){
    long af = *(const long*)&xs[lrow * 136 + kc * 32 + lq * 8];
    #pragma unroll
    for (int nt = 0; nt < 8; ++nt){
      long bf = WswV[((wv * 8 + nt) * 4 + kc) * 64 + L];
      acc[nt] = mfma16f8(af, bf, acc[nt]);
    }
  }
  #pragma unroll
  for (int nt = 0; nt < 8; ++nt){
    int gcol = wv * 128 + nt * 16 + lrow;
    int gt = gcol >> 8, w2 = (gcol >> 5) & 7, nt2 = (gcol >> 4) & 1;
    int tid2 = w2 * 64 + lq * 16 + lrow;
    #pragma unroll
    for (int r = 0; r < 4; ++r)
      sbuf[tid2 * 32 + gt * 8 + nt2 * 4 + r] = f2fp8(acc[nt][r]);
  }
  __syncthreads();
  long gbase = ((long)blk * 512 + tid) * 32;
  *(i32x4*)&gin[gbase]      = *(const i32x4*)&sbuf[tid * 32];
  *(i32x4*)&gin[gbase + 16] = *(const i32x4*)&sbuf[tid * 32 + 16];
}

// ---------- bidirectional LSTM ----------
// grid = 64 blocks x 512 threads (8 waves, 2/SIMD). dir = blockIdx>>4,
// slice = blockIdx&15 (16 batch rows). Wave w owns h-cols [w*32,w*32+32) x 4 gates.
// ALL weights register-resident (char KC=9 incl. x; word KC=8 h-only, x via gin).
// h double-buffered in LDS -> ONE barrier per step. c state + last-h in VGPRs.
template<int KC, int XDIM, int SA, bool GIN>
DEV void lstm_body(u8* abuf, const u8* __restrict__ xbuf, const u8* __restrict__ gin,
                   const u8* __restrict__ Wsw, const float* __restrict__ bias,
                   const int* __restrict__ lens, us16* __restrict__ hout,
                   int b0, int hcol0, bool rev, long ginBase)
{
  constexpr int BUF = 16 * SA;
  const int tid = threadIdx.x;
  const int w = tid >> 6, L = tid & 63;
  const int lrow = L & 15, lq = L >> 4;
  const long* WswV = (const long*)Wsw;

  // resident weights
  long wr[4][2][KC];
  #pragma unroll
  for (int gt = 0; gt < 4; ++gt)
    #pragma unroll
    for (int nt = 0; nt < 2; ++nt)
      #pragma unroll
      for (int kc = 0; kc < KC; ++kc)
        wr[gt][nt][kc] = WswV[(((w * 4 + gt) * 2 + nt) * KC + kc) * 64 + L];

  float bv[4][2];
  if constexpr (!GIN){
    #pragma unroll
    for (int gt = 0; gt < 4; ++gt)
      #pragma unroll
      for (int nt = 0; nt < 2; ++nt)
        bv[gt][nt] = bias[gt * 256 + w * 32 + nt * 16 + lrow];
  }

  unsigned lpack = 0;
  #pragma unroll
  for (int r = 0; r < 4; ++r)
    lpack |= (unsigned)lens[b0 + lq * 4 + r] << (8 * r);

  float cst[2][4];
  u8 hreg[2][4];
  #pragma unroll
  for (int nt = 0; nt < 2; ++nt)
    #pragma unroll
    for (int r = 0; r < 4; ++r){ cst[nt][r] = 0.0f; hreg[nt][r] = 0; }

  // zero h region of buffer 0
  for (int e = tid; e < 16 * 32; e += 512)
    *(long*)&abuf[(e >> 5) * SA + (e & 31) * 8] = 0;

  const int t0 = rev ? 199 : 0;
  i32x4 gA{}, gB{};
  if constexpr (GIN){
    const u8* gp = gin + ((ginBase + t0) * 512 + tid) * 32;
    gA = *(const i32x4*)gp; gB = *(const i32x4*)(gp + 16);
  } else {
    if (tid < (16 * XDIM) >> 3){
      int r = tid / (XDIM >> 3), c8 = (tid % (XDIM >> 3)) * 8;
      *(long*)&abuf[r * SA + 256 + c8] =
        *(const long*)&xbuf[((long)(b0 + r) * 200 + t0) * XDIM + c8];
    }
  }
  __syncthreads();

  for (int tau = 0; tau < 200; ++tau){
    const int t = rev ? (199 - tau) : tau;
    u8* cur = abuf + (tau & 1) * BUF;
    u8* nxt = abuf + ((tau & 1) ^ 1) * BUF;

    f32x4 acc[4][2];
    if constexpr (GIN){
      int g[8];
      *(i32x4*)&g[0] = gA; *(i32x4*)&g[4] = gB;
      #pragma unroll
      for (int gt = 0; gt < 4; ++gt)
        #pragma unroll
        for (int nt = 0; nt < 2; ++nt){
          int dw = g[gt * 2 + nt];
          acc[gt][nt] = (f32x4){fp8tof<0>(dw), fp8tof<1>(dw), fp8tof<2>(dw), fp8tof<3>(dw)};
        }
      int tn = (tau < 199) ? (rev ? 198 - tau : tau + 1) : t;   // prefetch next step
      const u8* gp = gin + ((ginBase + tn) * 512 + tid) * 32;
      gA = *(const i32x4*)gp; gB = *(const i32x4*)(gp + 16);
    } else {
      #pragma unroll
      for (int gt = 0; gt < 4; ++gt)
        #pragma unroll
        for (int nt = 0; nt < 2; ++nt){
          float b = bv[gt][nt];
          acc[gt][nt] = (f32x4){b, b, b, b};
        }
    }

    #pragma unroll
    for (int kc = 0; kc < KC; ++kc){
      long af = *(const long*)&cur[lrow * SA + kc * 32 + lq * 8];
      #pragma unroll
      for (int gt = 0; gt < 4; ++gt)
        #pragma unroll
        for (int nt = 0; nt < 2; ++nt)
          acc[gt][nt] = mfma16f8(af, wr[gt][nt][kc], acc[gt][nt]);
    }

    // cell epilogue: new h -> nxt buffer (+global); masked rows carry old h
    #pragma unroll
    for (int r = 0; r < 4; ++r){
      const int bm = lq * 4 + r;
      const bool mk = t < (int)((lpack >> (8 * r)) & 255u);
      const long gbase = ((long)(b0 + bm) * 200 + t) * 512 + hcol0;
      #pragma unroll
      for (int nt = 0; nt < 2; ++nt){
        float gi = acc[0][nt][r];
        float gf = acc[1][nt][r];
        float gg = acc[2][nt][r];
        float go = acc[3][nt][r];
        float cn = fsig(gf) * cst[nt][r] + fsig(gi) * ftanh(gg);
        float hn = fsig(go) * ftanh(cn);
        const int col = w * 32 + nt * 16 + lrow;
        u8 hb;
        if (mk){
          cst[nt][r] = cn;
          hb = f2fp8(hn);
          hreg[nt][r] = hb;
          hout[gbase + col] = f2bf(hn);
        } else {
          hb = hreg[nt][r];
          hout[gbase + col] = 0;
        }
        nxt[bm * SA + col] = hb;
      }
    }

    if constexpr (!GIN){
      if (tau < 199){
        int tn = rev ? (198 - tau) : (tau + 1);
        if (tid < (16 * XDIM) >> 3){
          int r = tid / (XDIM >> 3), c8 = (tid % (XDIM >> 3)) * 8;
          *(long*)&nxt[r * SA + 256 + c8] =
            *(const long*)&xbuf[((long)(b0 + r) * 200 + tn) * XDIM + c8];
        }
      }
    }
    __syncthreads();
  }
}

__global__ __launch_bounds__(512, 2) void k_lstm(
    const u8* __restrict__ char_vec, const u8* __restrict__ gin,
    const u8* __restrict__ wsw_cf, const u8* __restrict__ wsw_cb,
    const u8* __restrict__ wsw_wf, const u8* __restrict__ wsw_wb,
    const float* __restrict__ b_cf, const float* __restrict__ b_cb,
    const int* __restrict__ len_char, const int* __restrict__ len_word,
    us16* __restrict__ h_char, us16* __restrict__ h_word)
{
  const int dir   = blockIdx.x >> 4;
  const int slice = blockIdx.x & 15;
  const int b0 = slice * 16;
  __shared__ __align__(16) u8 abuf[2 * 16 * 304];

  if (dir == 0)
    lstm_body<9, 32, 304, false>(abuf, char_vec, nullptr, wsw_cf, b_cf,
                                 len_char, h_char, b0, 0, false, 0);
  else if (dir == 1)
    lstm_body<9, 32, 304, false>(abuf, char_vec, nullptr, wsw_cb, b_cb,
                                 len_char, h_char, b0, 256, true, 0);
  else if (dir == 2)
    lstm_body<8, 0, 280, true>(abuf, nullptr, gin, wsw_wf, nullptr,
                               len_word, h_word, b0, 0, false, (long)slice * 200);
  else
    lstm_body<8, 0, 280, true>(abuf, nullptr, gin, wsw_wb, nullptr,
                               len_word, h_word, b0, 256, true, (long)(16 + slice) * 200);
}

// ---------- generic FF GEMM: out = softplus(A[M,K]bf16 @ Wsw^T + bias) ----------
__global__ __launch_bounds__(256) void k_gemm(
    const us16* __restrict__ A, int KC, const us16* __restrict__ Wsw,
    const float* __restrict__ bias, int N,
    void* __restrict__ outp, int ostride, int ocol0, int out_f32)
{
  const int tid = threadIdx.x;
  const int w = tid >> 6, L = tid & 63;
  const int lrow = L & 15, lq = L >> 4;
  const int m0base = blockIdx.x * 128;
  const int ntbase = blockIdx.y * 8;
  const int Kd = KC * 32;
  __shared__ us16 At[128 * 40];            // 20 dw stride -> <=2-way banks
  f32x4 acc[8][2] = {};
  const short8* WswV = (const short8*)Wsw;
  const int srow = tid >> 1, scol = (tid & 1) * 16;

  for (int kc = 0; kc < KC; ++kc){
    const long abase = (long)(m0base + srow) * Kd + kc * 32 + scol;
    short8 v0 = *(const short8*)&A[abase];
    short8 v1 = *(const short8*)&A[abase + 8];
    *(short8*)&At[srow * 40 + scol] = v0;
    *(short8*)&At[srow * 40 + scol + 8] = v1;
    __syncthreads();
    short8 af0 = *(const short8*)&At[(w * 32 + lrow) * 40 + lq * 8];
    short8 af1 = *(const short8*)&At[(w * 32 + 16 + lrow) * 40 + lq * 8];
    #pragma unroll
    for (int nt = 0; nt < 8; ++nt){
      short8 bf = WswV[((ntbase + nt) * KC + kc) * 64 + L];
      acc[nt][0] = mfma16(af0, bf, acc[nt][0]);
      acc[nt][1] = mfma16(af1, bf, acc[nt][1]);
    }
    __syncthreads();
  }
  #pragma unroll
  for (int nt = 0; nt < 8; ++nt){
    const int col = (ntbase + nt) * 16 + lrow;
    if (col >= N) continue;
    const float bvv = bias[col];
    #pragma unroll
    for (int m0 = 0; m0 < 2; ++m0){
      #pragma unroll
      for (int r = 0; r < 4; ++r){
        float v = fsoftplus(acc[nt][m0][r] + bvv);
        const int row = m0base + w * 32 + m0 * 16 + lq * 4 + r;
        if (out_f32) ((float*)outp)[(long)row * ostride + ocol0 + col] = v;
        else         ((us16*)outp)[(long)row * ostride + ocol0 + col] = f2bf(v);
      }
    }
  }
}

// ---------- CRF NLL: one wave per batch row ----------
__global__ void k_crf(const float* __restrict__ logits, const int* __restrict__ tags,
                      const int* __restrict__ lens, const float* __restrict__ trans,
                      float* __restrict__ nll)
{
  const int b = blockIdx.x;
  const int lane = threadIdx.x;            // 64
  __shared__ float alpha[12];
  __shared__ float tmp[12];
  float tcol[12];
  if (lane < 12){
    #pragma unroll
    for (int i = 0; i < 12; ++i) tcol[i] = trans[i * 12 + lane];
    alpha[lane] = 0.0f;
  }
  const int len = lens[b];
  __syncthreads();
  for (int t = 0; t < len; ++t){
    float an = 0.0f;
    if (lane < 12){
      float mx = -3.0e38f;
      #pragma unroll
      for (int i = 0; i < 12; ++i) mx = fmaxf(mx, alpha[i] + tcol[i]);
      float ss = 0.0f;
      #pragma unroll
      for (int i = 0; i < 12; ++i)
        ss += __builtin_amdgcn_exp2f(1.4426950408889634f * (alpha[i] + tcol[i] - mx));
      an = logits[((long)b * 200 + t) * 12 + lane] + mx
         + 0.69314718055994531f * __builtin_amdgcn_logf(ss);
    }
    __syncthreads();
    if (lane < 12) alpha[lane] = an;
    __syncthreads();
  }
  if (lane < 12) tmp[lane] = alpha[lane] + trans[lane * 12 + 11];   // + trans[:,STOP]
  __syncthreads();
  float rs = 0.0f;
  for (int t = lane; t < len; t += 64){
    int tg = tags[b * 200 + t];
    int pv = (t == 0) ? 10 : tags[b * 200 + t - 1];                 // START=10
    rs += logits[((long)b * 200 + t) * 12 + tg] + trans[pv * 12 + tg];
  }
  #pragma unroll
  for (int off = 32; off > 0; off >>= 1) rs += __shfl_down(rs, off, 64);
  if (lane == 0){
    float mx = -3.0e38f;
    for (int i = 0; i < 12; ++i) mx = fmaxf(mx, tmp[i]);
    float ss = 0.0f;
    for (int i = 0; i < 12; ++i)
      ss += __builtin_amdgcn_exp2f(1.4426950408889634f * (tmp[i] - mx));
    float total = mx + 0.69314718055994531f * __builtin_amdgcn_logf(ss);
    rs += trans[tags[b * 200 + len - 1] * 12 + 11];                 // trans[last, STOP]
    nll[b] = total - rs;
  }
}

__global__ void k_sum(const float* __restrict__ nll, float* __restrict__ out){
  __shared__ float red[256];
  int t = threadIdx.x;
  red[t] = nll[t];
  __syncthreads();
  for (int s = 128; s > 0; s >>= 1){
    if (t < s) red[t] += red[t + s];
    __syncthreads();
  }
  if (t == 0) out[0] = red[0];
}

// ---------- launcher ----------
extern "C" void kernel_launch(void* const* d_in, const int* in_sizes, int n_in,
                              void* d_out, int out_size, void* d_ws, size_t ws_size,
                              hipStream_t stream)
{
  (void)in_sizes; (void)n_in; (void)out_size; (void)ws_size;
  const int*   characters = (const int*)  d_in[0];
  const float* words      = (const float*)d_in[1];
  const int*   tags       = (const int*)  d_in[2];
  const int*   len_char   = (const int*)  d_in[3];
  const int*   len_word   = (const int*)  d_in[4];
  const float* char_emb   = (const float*)d_in[5];
  const float* char_Wih_f = (const float*)d_in[6];
  const float* char_Whh_f = (const float*)d_in[7];
  const float* char_b_f   = (const float*)d_in[8];
  const float* char_Wih_b = (const float*)d_in[9];
  const float* char_Whh_b = (const float*)d_in[10];
  const float* char_b_b   = (const float*)d_in[11];
  const float* char_lin_W = (const float*)d_in[12];
  const float* char_lin_b = (const float*)d_in[13];
  const float* word_Wih_f = (const float*)d_in[14];
  const float* word_Whh_f = (const float*)d_in[15];
  const float* word_b_f   = (const float*)d_in[16];
  const float* word_Wih_b = (const float*)d_in[17];
  const float* word_Whh_b = (const float*)d_in[18];
  const float* word_b_b   = (const float*)d_in[19];
  const float* word_lin_W = (const float*)d_in[20];
  const float* word_lin_b = (const float*)d_in[21];
  const float* lin1_W     = (const float*)d_in[22];
  const float* lin1_b     = (const float*)d_in[23];
  const float* lin2_W     = (const float*)d_in[24];
  const float* lin2_b     = (const float*)d_in[25];
  const float* tag_W      = (const float*)d_in[26];
  const float* tag_b      = (const float*)d_in[27];
  const float* trans      = (const float*)d_in[28];

  char* ws = (char*)d_ws;
  size_t off = 0;
  auto take = [&](size_t bytes) -> char* {
    char* p = ws + off;
    off = (off + bytes + 511) & ~(size_t)511;
    return p;
  };
  u8*   char_vec = (u8*)take((size_t)256*200*32);          //  1.6 MB fp8
  u8*   words_f8 = (u8*)take((size_t)256*200*128);         //  6.3 MB fp8
  u8*   wsw_cf   = (u8*)take((size_t)64*9*512);
  u8*   wsw_cb   = (u8*)take((size_t)64*9*512);
  u8*   wsw_wf   = (u8*)take((size_t)64*8*512);            // h-part only (KC=8)
  u8*   wsw_wb   = (u8*)take((size_t)64*8*512);
  u8*   wswgin_f = (u8*)take((size_t)64*4*512);            // Wih B-frag (128 KB)
  u8*   wswgin_b = (u8*)take((size_t)64*4*512);
  us16* wswg1    = (us16*)take((size_t)32*16*512*2);
  us16* wswg2    = (us16*)take((size_t)16*16*512*2);
  us16* wswg3    = (us16*)take((size_t)32*23*512*2);
  us16* wswg4    = (us16*)take((size_t)16*16*512*2);
  us16* wswg5    = (us16*)take((size_t)8*8*512*2);
  float* logits  = (float*)take((size_t)51200*12*4);
  float* nll     = (float*)take((size_t)256*4);
  us16* h_char   = (us16*)take((size_t)51200*512*2);       // 50 MB
  us16* h_word   = (us16*)take((size_t)51200*512*2);       // 50 MB
  u8*   gin      = (u8*)take((size_t)2*3200*512*32);       // 100 MB; dead after k_lstm
  us16* x_cat    = (us16*)gin;   // 72 MB, written after k_lstm -> safe alias
  us16* x1 = h_char;   // dead after G1
  us16* x2 = h_word;   // dead after G2

  // preprocessing
  k_embed<<<6400, 256, 0, stream>>>(characters, char_emb, char_vec);
  k_cvt8<<<(256*200*128 + 255)/256, 256, 0, stream>>>(words, words_f8, 256*200*128);
  k_swz_lstm<<<(64*9*512 + 255)/256, 256, 0, stream>>>(char_Whh_f, char_Wih_f, 30, 9, wsw_cf);
  k_swz_lstm<<<(64*9*512 + 255)/256, 256, 0, stream>>>(char_Whh_b, char_Wih_b, 30, 9, wsw_cb);
  k_swz_lstm<<<(64*8*512 + 255)/256, 256, 0, stream>>>(word_Whh_f, word_Wih_f, 0, 8, wsw_wf);
  k_swz_lstm<<<(64*8*512 + 255)/256, 256, 0, stream>>>(word_Whh_b, word_Wih_b, 0, 8, wsw_wb);
  k_swz_gin<<<(64*4*512 + 255)/256, 256, 0, stream>>>(word_Wih_f, wswgin_f);
  k_swz_gin<<<(64*4*512 + 255)/256, 256, 0, stream>>>(word_Wih_b, wswgin_b);
  k_swz_ff<<<(32*16*512 + 255)/256, 256, 0, stream>>>(char_lin_W, 512, 512, 16, wswg1, 32*16*512);
  k_swz_ff<<<(16*16*512 + 255)/256, 256, 0, stream>>>(word_lin_W, 200, 512, 16, wswg2, 16*16*512);
  k_swz_ff<<<(32*23*512 + 255)/256, 256, 0, stream>>>(lin1_W, 512, 712, 23, wswg3, 32*23*512);
  k_swz_ff<<<(16*16*512 + 255)/256, 256, 0, stream>>>(lin2_W, 256, 512, 16, wswg4, 16*16*512);
  k_swz_ff<<<(8*8*512 + 255)/256, 256, 0, stream>>>(tag_W, 12, 256, 8, wswg5, 8*8*512);

  // gin precompute (word Wih.x + b, fp8, lane-layout)
  k_gin<<<6400, 512, 0, stream>>>(words_f8, wswgin_f, wswgin_b, word_b_f, word_b_b, gin);

  // recurrences: 64 blocks x 512 thr, fully register-resident weights
  k_lstm<<<64, 512, 0, stream>>>(char_vec, gin, wsw_cf, wsw_cb, wsw_wf, wsw_wb,
                                 char_b_f, char_b_b, len_char, len_word, h_char, h_word);

  // x_cat padding (x_cat aliases gin -> must run after k_lstm)
  k_zpad<<<4800, 256, 0, stream>>>(x_cat);

  // feed-forward chain (bf16)
  k_gemm<<<dim3(400, 4), 256, 0, stream>>>(h_char, 16, wswg1, char_lin_b, 512, x_cat, 736,   0, 0);
  k_gemm<<<dim3(400, 2), 256, 0, stream>>>(h_word, 16, wswg2, word_lin_b, 200, x_cat, 736, 512, 0);
  k_gemm<<<dim3(400, 4), 256, 0, stream>>>(x_cat, 23, wswg3, lin1_b, 512, x1, 512, 0, 0);
  k_gemm<<<dim3(400, 2), 256, 0, stream>>>(x1,    16, wswg4, lin2_b, 256, x2, 256, 0, 0);
  k_gemm<<<dim3(400, 1), 256, 0, stream>>>(x2,     8, wswg5, tag_b,   12, logits, 12, 0, 1);

  // CRF
  k_crf<<<256, 64, 0, stream>>>(logits, tags, len_char, trans, nll);
  k_sum<<<1, 256, 0, stream>>>(nll, (float*)d_out);
}